// Round 6
// baseline (1940.318 us; speedup 1.0000x reference)
//
#include <hip/hip_runtime.h>
#include <hip/hip_bf16.h>
#include <cstdint>
#include <cstddef>

#define Bsz 16384
#define HORsz 5

using bf16_t = __hip_bfloat16;
typedef __bf16 bf16x8 __attribute__((ext_vector_type(8)));
typedef float f32x4 __attribute__((ext_vector_type(4)));

__device__ __forceinline__ void gld_lds16(const void* g, void* l) {
  __builtin_amdgcn_global_load_lds((__attribute__((address_space(1))) void*)g,
                                   (__attribute__((address_space(3))) void*)l,
                                   16, 0, 0);
}

__device__ __forceinline__ float sigm(float x) { return 1.f / (1.f + __expf(-x)); }
__device__ __forceinline__ float tanh_fast(float x) {
  x = fminf(fmaxf(x, -20.f), 20.f);
  float e = __expf(2.f * x);
  return (e - 1.f) / (e + 1.f);
}

// XCD-aware swizzle: blocks b, b+8, b+16 ... (same XCD under b%8 round-robin)
// sweep all n-tiles of one m-tile consecutively. Requires NB_M % 8 == 0.
__device__ __forceinline__ void swz(int b, int nbn, int& n, int& m) {
  const int x = b & 7;
  const int k = b >> 3;
  n = k % nbn;
  m = x + 8 * (k / nbn);
}

// Fragment layout (FL) bf16 [R,C]: 1KB chunk = 16 rows x 32 cols; lane l <-> bytes [16l,16l+16).
// chunk(rg,kg) at ((rg*ca)+cofs+kg)*1024 ; within: (((col>>3)&3)*16 + (row&15))*16 + (col&7)*2
__device__ __forceinline__ size_t fl_off(int row, int col, int ca, int cofs) {
  return (size_t)((row >> 4) * ca + cofs + (col >> 5)) * 1024
       + (size_t)((((col >> 3) & 3) * 16 + (row & 15)) * 16 + (col & 7) * 2);
}

// fp32 row-major [R,C] -> bf16 FL.
__global__ void __launch_bounds__(256) pack_fl(const float* __restrict__ src,
                                               char* __restrict__ dst,
                                               int C, int cs, int npieces) {
  const int p = blockIdx.x * 256 + threadIdx.x;
  if (p >= npieces) return;
  const int chunk = p >> 6, wi = p & 63;
  const int colgrp = wi >> 4, r15 = wi & 15;
  const int rowgrp = chunk >> cs, kg = chunk & ((1 << cs) - 1);
  const int row = rowgrp * 16 + r15;
  const int col = kg * 32 + colgrp * 8;
  const float* s = src + (size_t)row * C + col;
  bf16x8 v;
  #pragma unroll
  for (int j = 0; j < 8; ++j) v[j] = (__bf16)s[j];
  *(bf16x8*)(dst + (size_t)p * 16) = v;
}

// Fused GRU cell, LDS double-buffered, single barrier per K-step.
// Block: 128 rows x 64 chans x 3 gates. K=512 (16 kg). 20KB/buffer x2.
__global__ void __launch_bounds__(256, 4) gru_fused2(
    const char* __restrict__ Afl, int ca,   // A = hprev FL, K chunks 0..15
    const char* __restrict__ Wfl,           // whh FL [1536,512], nkg=16
    const float* __restrict__ x, int ldx,   // fp32, 4 cols used
    const float* __restrict__ w_ih, const float* __restrict__ b_ih,
    const float* __restrict__ b_hh,
    char* __restrict__ Ofl, int co, int kofs)
{
  __shared__ char smem[40960];
  const int t = threadIdx.x, w = t >> 6, lane = t & 63;
  int bn, bm;
  swz(blockIdx.x, 8, bn, bm);
  const int m0 = bm * 128;
  const int n0 = bn * 64;
  const int wm = (w >> 1) * 64, wc = (w & 1) * 32;

  // staging: 20 chunks/kg; wave w stages idx = w*5+s
  const char* gsrc[5];
  int loff[5];
  #pragma unroll
  for (int s = 0; s < 5; ++s) {
    const int idx = w * 5 + s;
    if (idx < 8) {
      gsrc[s] = Afl + (size_t)((m0 >> 4) + idx) * ca * 1024 + lane * 16;
    } else {
      const int c = idx - 8, g = c >> 2, cr = c & 3;
      gsrc[s] = Wfl + (size_t)(g * 32 + (n0 >> 4) + cr) * 16 * 1024 + lane * 16;
    }
    loff[s] = idx * 1024;
  }

  f32x4 acc[3][4][2];
  const f32x4 zero = {0.f, 0.f, 0.f, 0.f};
  #pragma unroll
  for (int g = 0; g < 3; ++g)
    #pragma unroll
    for (int i = 0; i < 4; ++i)
      #pragma unroll
      for (int jt = 0; jt < 2; ++jt) acc[g][i][jt] = zero;

  // prologue: stage kg=0 into buf0
  #pragma unroll
  for (int s = 0; s < 5; ++s)
    gld_lds16(gsrc[s], smem + loff[s]);

  for (int kg = 0; kg < 16; ++kg) {
    __syncthreads();   // drains stage(kg) (in flight one full iteration)
    const char* cur = smem + (kg & 1) * 20480;
    if (kg + 1 < 16) {
      char* nxt = smem + ((kg + 1) & 1) * 20480;
      #pragma unroll
      for (int s = 0; s < 5; ++s)
        gld_lds16(gsrc[s] + (size_t)(kg + 1) * 1024, nxt + loff[s]);
    }
    bf16x8 af[4];
    #pragma unroll
    for (int i = 0; i < 4; ++i)
      af[i] = *(const bf16x8*)(cur + ((wm >> 4) + i) * 1024 + lane * 16);
    #pragma unroll
    for (int g = 0; g < 3; ++g)
      #pragma unroll
      for (int jt = 0; jt < 2; ++jt) {
        const bf16x8 bv = *(const bf16x8*)(cur + 8192 + (g * 4 + (w & 1) * 2 + jt) * 1024 + lane * 16);
        #pragma unroll
        for (int i = 0; i < 4; ++i)
          acc[g][i][jt] = __builtin_amdgcn_mfma_f32_16x16x32_bf16(af[i], bv, acc[g][i][jt], 0, 0, 0);
      }
  }

  const int lr = lane & 15, q4 = (lane >> 4) * 4;
  __syncthreads();                 // all waves done with buf0 reads; reuse for repack
  char* rep = smem + w * 4096;     // wave-private repack slice (4 chunks)
  #pragma unroll
  for (int jt = 0; jt < 2; ++jt) {
    const int c = n0 + wc + jt * 16 + lr;
    const float4 wr  = *(const float4*)(w_ih + (size_t)c * 4);
    const float4 wz  = *(const float4*)(w_ih + (size_t)(c + 512) * 4);
    const float4 wnn = *(const float4*)(w_ih + (size_t)(c + 1024) * 4);
    const float bir = b_ih[c], biz = b_ih[c + 512], bin = b_ih[c + 1024];
    const float bhr = b_hh[c], bhz = b_hh[c + 512], bhn = b_hh[c + 1024];
    const int wbase = ((jt * 2 + (lr >> 3)) * 16 + q4) * 16 + (lr & 7) * 2;
    #pragma unroll
    for (int i = 0; i < 4; ++i) {
      #pragma unroll
      for (int r4 = 0; r4 < 4; ++r4) {
        const int row = m0 + wm + i * 16 + q4 + r4;
        const float4 xv = *(const float4*)(x + (size_t)row * ldx);
        const float gir = bir + xv.x * wr.x  + xv.y * wr.y  + xv.z * wr.z  + xv.w * wr.w;
        const float giz = biz + xv.x * wz.x  + xv.y * wz.y  + xv.z * wz.z  + xv.w * wz.w;
        const float gin = bin + xv.x * wnn.x + xv.y * wnn.y + xv.z * wnn.z + xv.w * wnn.w;
        const float rr = sigm(gir + acc[0][i][jt][r4] + bhr);
        const float zz = sigm(giz + acc[1][i][jt][r4] + bhz);
        const float nn = tanh_fast(gin + rr * (acc[2][i][jt][r4] + bhn));
        const float hp = (float)*(const __bf16*)(Afl + fl_off(row, c, ca, 0));
        *(__bf16*)(rep + i * 1024 + wbase + r4 * 16) = (__bf16)((1.f - zz) * nn + zz * hp);
      }
    }
  }
  // rep slice is wave-private: same-wave LDS RAW handled by compiler lgkmcnt
  const int rg0 = (m0 >> 4) + (wm >> 4);
  const int cg = kofs + (n0 >> 5) + (w & 1);
  #pragma unroll
  for (int i = 0; i < 4; ++i) {
    const bf16x8 v = *(const bf16x8*)(rep + i * 1024 + lane * 16);
    *(bf16x8*)(Ofl + ((size_t)(rg0 + i) * co + cg) * 1024 + lane * 16) = v;
  }
}

// Generic FL GEMM, block 128x128, XCD-swizzled, LDS dbuf single-barrier.
// MODE 2 (fc):   O1 = bf16(v) FL ; O2 = bf16(relu(v)) FL — coalesced via LDS repack
// MODE 3 (mlp1): dxy[slice][row][0..3] partials of relu(v)*w2^T, slice = bn*2+(w&1)
template <int MODE>
__global__ void __launch_bounds__(256, 4) gemm_fl2(
    const char* __restrict__ Afl, int ca,
    const char* __restrict__ Bfl, int nkg, int nbn,
    const float* __restrict__ bias,
    char* __restrict__ O1, char* __restrict__ O2, int co,
    const float* __restrict__ w2, float* __restrict__ dxy)
{
  __shared__ char smem[32768];
  const int t = threadIdx.x, w = t >> 6, lane = t & 63;
  int bn, bm;
  swz(blockIdx.x, nbn, bn, bm);
  const int m0 = bm * 128, n0 = bn * 128;
  const int wm = (w >> 1) * 64, wn = (w & 1) * 64;

  const char* gsrc[4];
  int loff[4];
  #pragma unroll
  for (int s = 0; s < 4; ++s) {
    const int idx = w * 4 + s;
    if (idx < 8) gsrc[s] = Afl + (size_t)((m0 >> 4) + idx) * ca * 1024 + lane * 16;
    else         gsrc[s] = Bfl + (size_t)((n0 >> 4) + idx - 8) * nkg * 1024 + lane * 16;
    loff[s] = idx * 1024;
  }

  f32x4 acc[4][4];
  const f32x4 zero = {0.f, 0.f, 0.f, 0.f};
  #pragma unroll
  for (int i = 0; i < 4; ++i)
    #pragma unroll
    for (int j = 0; j < 4; ++j) acc[i][j] = zero;

  #pragma unroll
  for (int s = 0; s < 4; ++s)
    gld_lds16(gsrc[s], smem + loff[s]);

  for (int kg = 0; kg < nkg; ++kg) {
    __syncthreads();
    const char* cur = smem + (kg & 1) * 16384;
    if (kg + 1 < nkg) {
      char* nxt = smem + ((kg + 1) & 1) * 16384;
      #pragma unroll
      for (int s = 0; s < 4; ++s)
        gld_lds16(gsrc[s] + (size_t)(kg + 1) * 1024, nxt + loff[s]);
    }
    bf16x8 af[4], bv[4];
    #pragma unroll
    for (int i = 0; i < 4; ++i)
      af[i] = *(const bf16x8*)(cur + ((wm >> 4) + i) * 1024 + lane * 16);
    #pragma unroll
    for (int j = 0; j < 4; ++j)
      bv[j] = *(const bf16x8*)(cur + 8192 + ((wn >> 4) + j) * 1024 + lane * 16);
    #pragma unroll
    for (int i = 0; i < 4; ++i)
      #pragma unroll
      for (int j = 0; j < 4; ++j)
        acc[i][j] = __builtin_amdgcn_mfma_f32_16x16x32_bf16(af[i], bv[j], acc[i][j], 0, 0, 0);
  }

  const int lr = lane & 15, q4 = (lane >> 4) * 4;
  if (MODE == 2) {
    __syncthreads();               // reuse smem buf0 for repack
    char* rep = smem + w * 2048;   // wave-private, 2 chunks, reused per i
    const int rgb = (m0 >> 4) + (wm >> 4);
    const int cgb = (n0 >> 5) + (wn >> 5);
    for (int i = 0; i < 4; ++i) {
      #pragma unroll
      for (int j = 0; j < 4; ++j) {
        const int col = n0 + wn + j * 16 + lr;
        const float bvv = bias[col];
        const int wbase = (((j & 1) * 2 + (lr >> 3)) * 16 + q4) * 16 + (lr & 7) * 2;
        #pragma unroll
        for (int r = 0; r < 4; ++r) {
          const float v = acc[i][j][r] + bvv;
          *(__bf16*)(rep + (j >> 1) * 1024 + wbase + r * 16) = (__bf16)v;
        }
      }
      // wave-private slice: same-wave ordering via lgkmcnt, no barrier needed
      #pragma unroll
      for (int jc = 0; jc < 2; ++jc) {
        const bf16x8 v = *(const bf16x8*)(rep + jc * 1024 + lane * 16);
        const size_t cb = ((size_t)(rgb + i) * co + cgb + jc) * 1024 + lane * 16;
        *(bf16x8*)(O1 + cb) = v;
        bf16x8 vr;
        #pragma unroll
        for (int e = 0; e < 8; ++e) vr[e] = (__bf16)fmaxf((float)v[e], 0.f);
        *(bf16x8*)(O2 + cb) = vr;
      }
    }
  } else {
    const int slice = bn * 2 + (w & 1);
    #pragma unroll
    for (int i = 0; i < 4; ++i) {
      float v[4][4];   // [r][o]
      #pragma unroll
      for (int r = 0; r < 4; ++r)
        #pragma unroll
        for (int o = 0; o < 4; ++o) v[r][o] = 0.f;
      #pragma unroll
      for (int j = 0; j < 4; ++j) {
        const int col = n0 + wn + j * 16 + lr;
        const float bvv = bias[col];
        const float w20 = w2[col], w21 = w2[2048 + col], w22 = w2[4096 + col], w23 = w2[6144 + col];
        #pragma unroll
        for (int r = 0; r < 4; ++r) {
          const float pv = fmaxf(acc[i][j][r] + bvv, 0.f);
          v[r][0] += pv * w20; v[r][1] += pv * w21; v[r][2] += pv * w22; v[r][3] += pv * w23;
        }
      }
      #pragma unroll
      for (int m = 1; m <= 8; m <<= 1)
        #pragma unroll
        for (int r = 0; r < 4; ++r)
          #pragma unroll
          for (int o = 0; o < 4; ++o) v[r][o] += __shfl_xor(v[r][o], m);
      if (lr == 0) {
        #pragma unroll
        for (int r = 0; r < 4; ++r) {
          const int row = m0 + wm + i * 16 + q4 + r;
          float4 vv = make_float4(v[r][0], v[r][1], v[r][2], v[r][3]);
          *(float4*)(dxy + ((size_t)slice * Bsz + row) * 4) = vv;
        }
      }
    }
  }
}

// xy += sum(dxy slices) + b2; out[:,istep,:] = xy
__global__ void __launch_bounds__(256) finalize(
    const float* __restrict__ dxy, const float* __restrict__ b2,
    float* __restrict__ xy, float* __restrict__ out, int istep)
{
  const int b = blockIdx.x * 256 + threadIdx.x;
  float4 s = *(const float4*)b2;
  #pragma unroll 8
  for (int sl = 0; sl < 32; ++sl) {
    const float4 d = *(const float4*)(dxy + ((size_t)sl * Bsz + b) * 4);
    s.x += d.x; s.y += d.y; s.z += d.z; s.w += d.w;
  }
  float4 xv = *(const float4*)(xy + (size_t)b * 4);
  xv.x += s.x; xv.y += s.y; xv.z += s.z; xv.w += s.w;
  *(float4*)(xy + (size_t)b * 4) = xv;
  *(float4*)(out + (size_t)b * 20 + istep * 4) = xv;
}

extern "C" void kernel_launch(void* const* d_in, const int* in_sizes, int n_in,
                              void* d_out, int out_size, void* d_ws, size_t ws_size,
                              hipStream_t stream)
{
  const float* pv   = (const float*)d_in[0];
  const float* ptf  = (const float*)d_in[1];
  const float* w_ih = (const float*)d_in[2];
  const float* w_hh = (const float*)d_in[3];
  const float* b_ih = (const float*)d_in[4];
  const float* b_hh = (const float*)d_in[5];
  const float* w_fc = (const float*)d_in[6];
  const float* b_fc = (const float*)d_in[7];
  const float* w1   = (const float*)d_in[8];
  const float* b1   = (const float*)d_in[9];
  const float* w2   = (const float*)d_in[10];
  const float* b2   = (const float*)d_in[11];
  float* out = (float*)d_out;

  char* p = (char*)d_ws;
  auto carve = [&](size_t bytes) {
    char* r = p;
    p += (bytes + 255) & ~(size_t)255;
    return r;
  };
  char*  hxF   = carve((size_t)Bsz * 512 * 2);     // FL ca=16
  char*  hxrF  = carve((size_t)Bsz * 512 * 2);     // FL ca=16
  char*  hcatF = carve((size_t)Bsz * 1024 * 2);    // FL ca=32: h1 kg 0..15, h2 kg 16..31
  float* dxy   = (float*)carve((size_t)32 * Bsz * 4 * 4);
  float* xy    = (float*)carve((size_t)Bsz * 4 * 4);
  char*  whhF  = carve((size_t)1536 * 512 * 2);    // FL nkg=16
  char*  wfcF  = carve((size_t)512 * 1024 * 2);    // FL nkg=32
  char*  w1F   = carve((size_t)2048 * 512 * 2);    // FL nkg=16

  pack_fl<<<(1536 * 512 / 8 + 255) / 256, 256, 0, stream>>>(w_hh, whhF, 512, 4, 1536 * 512 / 8);
  pack_fl<<<(512 * 1024 / 8 + 255) / 256, 256, 0, stream>>>(w_fc, wfcF, 1024, 5, 512 * 1024 / 8);
  pack_fl<<<(2048 * 512 / 8 + 255) / 256, 256, 0, stream>>>(w1, w1F, 512, 4, 2048 * 512 / 8);
  pack_fl<<<(Bsz * 512 / 8 + 255) / 256, 256, 0, stream>>>(ptf, hxF, 512, 4, Bsz * 512 / 8);
  hipMemsetAsync(xy, 0, (size_t)Bsz * 4 * 4, stream);

  for (int i = 0; i < HORsz; ++i) {
    // h1 = GRUCell(xy, hx) -> hcat kg 0..15
    gru_fused2<<<1024, 256, 0, stream>>>(
        hxF, 16, whhF, xy, 4, w_ih, b_ih, b_hh, hcatF, 32, 0);
    // h2 = GRUCell(pv[:,i], h1) -> hcat kg 16..31
    gru_fused2<<<1024, 256, 0, stream>>>(
        hcatF, 32, whhF, pv + i * 4, HORsz * 4, w_ih, b_ih, b_hh, hcatF, 32, 16);
    // hx = hcat @ w_fc^T + b_fc ; hxr = relu(hx) (both FL, coalesced stores)
    gemm_fl2<2><<<512, 256, 0, stream>>>(
        hcatF, 32, wfcF, 32, 4, b_fc, hxF, hxrF, 16, nullptr, nullptr);
    // dxy partials = relu(relu-gemm) @ w2^T  (mlp1+mlp2 fused)
    gemm_fl2<3><<<2048, 256, 0, stream>>>(
        hxrF, 16, w1F, 16, 16, b1, nullptr, nullptr, 0, w2, dxy);
    // xy += sum + b2; out
    finalize<<<Bsz / 256, 256, 0, stream>>>(dxy, b2, xy, out, i);
  }
}

// Round 7
// 1071.873 us; speedup vs baseline: 1.8102x; 1.8102x over previous
//
#include <hip/hip_runtime.h>
#include <hip/hip_bf16.h>
#include <cstdint>
#include <cstddef>

#define Bsz 16384
#define HORsz 5

using bf16_t = __hip_bfloat16;
typedef __bf16 bf16x8 __attribute__((ext_vector_type(8)));
typedef float f32x4 __attribute__((ext_vector_type(4)));

__device__ __forceinline__ void gld_lds16(const void* g, void* l) {
  __builtin_amdgcn_global_load_lds((__attribute__((address_space(1))) void*)g,
                                   (__attribute__((address_space(3))) void*)l,
                                   16, 0, 0);
}

__device__ __forceinline__ float sigm(float x) { return 1.f / (1.f + __expf(-x)); }
__device__ __forceinline__ float tanh_fast(float x) {
  x = fminf(fmaxf(x, -20.f), 20.f);
  float e = __expf(2.f * x);
  return (e - 1.f) / (e + 1.f);
}

// XCD-aware swizzle: blocks b, b+8, b+16 ... (same XCD under b%8 round-robin)
// sweep all n-tiles of one m-tile consecutively. Requires NB_M % 8 == 0.
__device__ __forceinline__ void swz(int b, int nbn, int& n, int& m) {
  const int x = b & 7;
  const int k = b >> 3;
  n = k % nbn;
  m = x + 8 * (k / nbn);
}

// Fragment layout (FL) bf16 [R,C]: 1KB chunk = 16 rows x 32 cols; lane l <-> bytes [16l,16l+16).
// chunk(rg,kg) at ((rg*ca)+cofs+kg)*1024 ; within: (((col>>3)&3)*16 + (row&15))*16 + (col&7)*2
__device__ __forceinline__ size_t fl_off(int row, int col, int ca, int cofs) {
  return (size_t)((row >> 4) * ca + cofs + (col >> 5)) * 1024
       + (size_t)((((col >> 3) & 3) * 16 + (row & 15)) * 16 + (col & 7) * 2);
}

// fp32 row-major [R,C] -> bf16 FL.
__global__ void __launch_bounds__(256) pack_fl(const float* __restrict__ src,
                                               char* __restrict__ dst,
                                               int C, int cs, int npieces) {
  const int p = blockIdx.x * 256 + threadIdx.x;
  if (p >= npieces) return;
  const int chunk = p >> 6, wi = p & 63;
  const int colgrp = wi >> 4, r15 = wi & 15;
  const int rowgrp = chunk >> cs, kg = chunk & ((1 << cs) - 1);
  const int row = rowgrp * 16 + r15;
  const int col = kg * 32 + colgrp * 8;
  const float* s = src + (size_t)row * C + col;
  bf16x8 v;
  #pragma unroll
  for (int j = 0; j < 8; ++j) v[j] = (__bf16)s[j];
  *(bf16x8*)(dst + (size_t)p * 16) = v;
}

// Fused GRU cell, LDS double-buffered, single barrier per K-step.
// Block: 128 rows x 64 chans x 3 gates. K=512 (16 kg). 20KB/buffer x2.
// NOTE: __launch_bounds__(256,2) — (256,4) forces VGPR cap 128 < ~220 live regs
// and spills accumulators to scratch (round 6: WRITE 330MB, 150us/dispatch).
__global__ void __launch_bounds__(256, 2) gru_fused2(
    const char* __restrict__ Afl, int ca,   // A = hprev FL, K chunks 0..15
    const char* __restrict__ Wfl,           // whh FL [1536,512], nkg=16
    const float* __restrict__ x, int ldx,   // fp32, 4 cols used
    const float* __restrict__ w_ih, const float* __restrict__ b_ih,
    const float* __restrict__ b_hh,
    char* __restrict__ Ofl, int co, int kofs)
{
  __shared__ char smem[40960];
  const int t = threadIdx.x, w = t >> 6, lane = t & 63;
  int bn, bm;
  swz(blockIdx.x, 8, bn, bm);
  const int m0 = bm * 128;
  const int n0 = bn * 64;
  const int wm = (w >> 1) * 64, wc = (w & 1) * 32;

  // staging: 20 chunks/kg; wave w stages idx = w*5+s
  const char* gsrc[5];
  int loff[5];
  #pragma unroll
  for (int s = 0; s < 5; ++s) {
    const int idx = w * 5 + s;
    if (idx < 8) {
      gsrc[s] = Afl + (size_t)((m0 >> 4) + idx) * ca * 1024 + lane * 16;
    } else {
      const int c = idx - 8, g = c >> 2, cr = c & 3;
      gsrc[s] = Wfl + (size_t)(g * 32 + (n0 >> 4) + cr) * 16 * 1024 + lane * 16;
    }
    loff[s] = idx * 1024;
  }

  f32x4 acc[3][4][2];
  const f32x4 zero = {0.f, 0.f, 0.f, 0.f};
  #pragma unroll
  for (int g = 0; g < 3; ++g)
    #pragma unroll
    for (int i = 0; i < 4; ++i)
      #pragma unroll
      for (int jt = 0; jt < 2; ++jt) acc[g][i][jt] = zero;

  // prologue: stage kg=0 into buf0
  #pragma unroll
  for (int s = 0; s < 5; ++s)
    gld_lds16(gsrc[s], smem + loff[s]);

  for (int kg = 0; kg < 16; ++kg) {
    __syncthreads();   // drains stage(kg) (in flight one full iteration)
    const char* cur = smem + (kg & 1) * 20480;
    if (kg + 1 < 16) {
      char* nxt = smem + ((kg + 1) & 1) * 20480;
      #pragma unroll
      for (int s = 0; s < 5; ++s)
        gld_lds16(gsrc[s] + (size_t)(kg + 1) * 1024, nxt + loff[s]);
    }
    bf16x8 af[4];
    #pragma unroll
    for (int i = 0; i < 4; ++i)
      af[i] = *(const bf16x8*)(cur + ((wm >> 4) + i) * 1024 + lane * 16);
    #pragma unroll
    for (int g = 0; g < 3; ++g)
      #pragma unroll
      for (int jt = 0; jt < 2; ++jt) {
        const bf16x8 bv = *(const bf16x8*)(cur + 8192 + (g * 4 + (w & 1) * 2 + jt) * 1024 + lane * 16);
        #pragma unroll
        for (int i = 0; i < 4; ++i)
          acc[g][i][jt] = __builtin_amdgcn_mfma_f32_16x16x32_bf16(af[i], bv, acc[g][i][jt], 0, 0, 0);
      }
  }

  const int lr = lane & 15, q4 = (lane >> 4) * 4;
  // Repack into buf0: all waves are past the kg=15 barrier, so every wave is
  // done reading buf0 (last read at kg=14). No barrier needed; rep is wave-private.
  char* rep = smem + w * 4096;
  #pragma unroll
  for (int jt = 0; jt < 2; ++jt) {
    const int c = n0 + wc + jt * 16 + lr;
    const float4 wr  = *(const float4*)(w_ih + (size_t)c * 4);
    const float4 wz  = *(const float4*)(w_ih + (size_t)(c + 512) * 4);
    const float4 wnn = *(const float4*)(w_ih + (size_t)(c + 1024) * 4);
    const float bir = b_ih[c], biz = b_ih[c + 512], bin = b_ih[c + 1024];
    const float bhr = b_hh[c], bhz = b_hh[c + 512], bhn = b_hh[c + 1024];
    const int wbase = ((jt * 2 + (lr >> 3)) * 16 + q4) * 16 + (lr & 7) * 2;
    #pragma unroll
    for (int i = 0; i < 4; ++i) {
      #pragma unroll
      for (int r4 = 0; r4 < 4; ++r4) {
        const int row = m0 + wm + i * 16 + q4 + r4;
        const float4 xv = *(const float4*)(x + (size_t)row * ldx);
        const float gir = bir + xv.x * wr.x  + xv.y * wr.y  + xv.z * wr.z  + xv.w * wr.w;
        const float giz = biz + xv.x * wz.x  + xv.y * wz.y  + xv.z * wz.z  + xv.w * wz.w;
        const float gin = bin + xv.x * wnn.x + xv.y * wnn.y + xv.z * wnn.z + xv.w * wnn.w;
        const float rr = sigm(gir + acc[0][i][jt][r4] + bhr);
        const float zz = sigm(giz + acc[1][i][jt][r4] + bhz);
        const float nn = tanh_fast(gin + rr * (acc[2][i][jt][r4] + bhn));
        const float hp = (float)*(const __bf16*)(Afl + fl_off(row, c, ca, 0));
        *(__bf16*)(rep + i * 1024 + wbase + r4 * 16) = (__bf16)((1.f - zz) * nn + zz * hp);
      }
    }
  }
  // rep slice is wave-private: same-wave LDS RAW handled by compiler lgkmcnt
  const int rg0 = (m0 >> 4) + (wm >> 4);
  const int cg = kofs + (n0 >> 5) + (w & 1);
  #pragma unroll
  for (int i = 0; i < 4; ++i) {
    const bf16x8 v = *(const bf16x8*)(rep + i * 1024 + lane * 16);
    *(bf16x8*)(Ofl + ((size_t)(rg0 + i) * co + cg) * 1024 + lane * 16) = v;
  }
}

// Generic FL GEMM, block 128x128, XCD-swizzled, LDS dbuf single-barrier.
// MODE 2 (fc):   O1 = bf16(v) FL ; O2 = bf16(relu(v)) FL — coalesced via LDS repack
// MODE 3 (mlp1): dxy[slice][row][0..3] partials of relu(v)*w2^T, slice = bn*2+(w&1)
template <int MODE>
__global__ void __launch_bounds__(256, 2) gemm_fl2(
    const char* __restrict__ Afl, int ca,
    const char* __restrict__ Bfl, int nkg, int nbn,
    const float* __restrict__ bias,
    char* __restrict__ O1, char* __restrict__ O2, int co,
    const float* __restrict__ w2, float* __restrict__ dxy)
{
  __shared__ char smem[32768];
  const int t = threadIdx.x, w = t >> 6, lane = t & 63;
  int bn, bm;
  swz(blockIdx.x, nbn, bn, bm);
  const int m0 = bm * 128, n0 = bn * 128;
  const int wm = (w >> 1) * 64, wn = (w & 1) * 64;

  const char* gsrc[4];
  int loff[4];
  #pragma unroll
  for (int s = 0; s < 4; ++s) {
    const int idx = w * 4 + s;
    if (idx < 8) gsrc[s] = Afl + (size_t)((m0 >> 4) + idx) * ca * 1024 + lane * 16;
    else         gsrc[s] = Bfl + (size_t)((n0 >> 4) + idx - 8) * nkg * 1024 + lane * 16;
    loff[s] = idx * 1024;
  }

  f32x4 acc[4][4];
  const f32x4 zero = {0.f, 0.f, 0.f, 0.f};
  #pragma unroll
  for (int i = 0; i < 4; ++i)
    #pragma unroll
    for (int j = 0; j < 4; ++j) acc[i][j] = zero;

  #pragma unroll
  for (int s = 0; s < 4; ++s)
    gld_lds16(gsrc[s], smem + loff[s]);

  for (int kg = 0; kg < nkg; ++kg) {
    __syncthreads();
    const char* cur = smem + (kg & 1) * 16384;
    if (kg + 1 < nkg) {
      char* nxt = smem + ((kg + 1) & 1) * 16384;
      #pragma unroll
      for (int s = 0; s < 4; ++s)
        gld_lds16(gsrc[s] + (size_t)(kg + 1) * 1024, nxt + loff[s]);
    }
    bf16x8 af[4], bv[4];
    #pragma unroll
    for (int i = 0; i < 4; ++i)
      af[i] = *(const bf16x8*)(cur + ((wm >> 4) + i) * 1024 + lane * 16);
    #pragma unroll
    for (int j = 0; j < 4; ++j)
      bv[j] = *(const bf16x8*)(cur + 8192 + ((wn >> 4) + j) * 1024 + lane * 16);
    #pragma unroll
    for (int i = 0; i < 4; ++i)
      #pragma unroll
      for (int j = 0; j < 4; ++j)
        acc[i][j] = __builtin_amdgcn_mfma_f32_16x16x32_bf16(af[i], bv[j], acc[i][j], 0, 0, 0);
  }

  const int lr = lane & 15, q4 = (lane >> 4) * 4;
  if (MODE == 2) {
    // buf0 free (all waves past final barrier); rep is wave-private
    char* rep = smem + w * 2048;
    const int rgb = (m0 >> 4) + (wm >> 4);
    const int cgb = (n0 >> 5) + (wn >> 5);
    for (int i = 0; i < 4; ++i) {
      #pragma unroll
      for (int j = 0; j < 4; ++j) {
        const int col = n0 + wn + j * 16 + lr;
        const float bvv = bias[col];
        const int wbase = (((j & 1) * 2 + (lr >> 3)) * 16 + q4) * 16 + (lr & 7) * 2;
        #pragma unroll
        for (int r = 0; r < 4; ++r) {
          const float v = acc[i][j][r] + bvv;
          *(__bf16*)(rep + (j >> 1) * 1024 + wbase + r * 16) = (__bf16)v;
        }
      }
      // wave-private slice: same-wave ordering via lgkmcnt, no barrier needed
      #pragma unroll
      for (int jc = 0; jc < 2; ++jc) {
        const bf16x8 v = *(const bf16x8*)(rep + jc * 1024 + lane * 16);
        const size_t cb = ((size_t)(rgb + i) * co + cgb + jc) * 1024 + lane * 16;
        *(bf16x8*)(O1 + cb) = v;
        bf16x8 vr;
        #pragma unroll
        for (int e = 0; e < 8; ++e) vr[e] = (__bf16)fmaxf((float)v[e], 0.f);
        *(bf16x8*)(O2 + cb) = vr;
      }
    }
  } else {
    const int slice = bn * 2 + (w & 1);
    #pragma unroll
    for (int i = 0; i < 4; ++i) {
      float v[4][4];   // [r][o]
      #pragma unroll
      for (int r = 0; r < 4; ++r)
        #pragma unroll
        for (int o = 0; o < 4; ++o) v[r][o] = 0.f;
      #pragma unroll
      for (int j = 0; j < 4; ++j) {
        const int col = n0 + wn + j * 16 + lr;
        const float bvv = bias[col];
        const float w20 = w2[col], w21 = w2[2048 + col], w22 = w2[4096 + col], w23 = w2[6144 + col];
        #pragma unroll
        for (int r = 0; r < 4; ++r) {
          const float pv = fmaxf(acc[i][j][r] + bvv, 0.f);
          v[r][0] += pv * w20; v[r][1] += pv * w21; v[r][2] += pv * w22; v[r][3] += pv * w23;
        }
      }
      #pragma unroll
      for (int m = 1; m <= 8; m <<= 1)
        #pragma unroll
        for (int r = 0; r < 4; ++r)
          #pragma unroll
          for (int o = 0; o < 4; ++o) v[r][o] += __shfl_xor(v[r][o], m);
      if (lr == 0) {
        #pragma unroll
        for (int r = 0; r < 4; ++r) {
          const int row = m0 + wm + i * 16 + q4 + r;
          float4 vv = make_float4(v[r][0], v[r][1], v[r][2], v[r][3]);
          *(float4*)(dxy + ((size_t)slice * Bsz + row) * 4) = vv;
        }
      }
    }
  }
}

// xy += sum(dxy slices) + b2; out[:,istep,:] = xy
__global__ void __launch_bounds__(256) finalize(
    const float* __restrict__ dxy, const float* __restrict__ b2,
    float* __restrict__ xy, float* __restrict__ out, int istep)
{
  const int b = blockIdx.x * 256 + threadIdx.x;
  float4 s = *(const float4*)b2;
  #pragma unroll 8
  for (int sl = 0; sl < 32; ++sl) {
    const float4 d = *(const float4*)(dxy + ((size_t)sl * Bsz + b) * 4);
    s.x += d.x; s.y += d.y; s.z += d.z; s.w += d.w;
  }
  float4 xv = *(const float4*)(xy + (size_t)b * 4);
  xv.x += s.x; xv.y += s.y; xv.z += s.z; xv.w += s.w;
  *(float4*)(xy + (size_t)b * 4) = xv;
  *(float4*)(out + (size_t)b * 20 + istep * 4) = xv;
}

extern "C" void kernel_launch(void* const* d_in, const int* in_sizes, int n_in,
                              void* d_out, int out_size, void* d_ws, size_t ws_size,
                              hipStream_t stream)
{
  const float* pv   = (const float*)d_in[0];
  const float* ptf  = (const float*)d_in[1];
  const float* w_ih = (const float*)d_in[2];
  const float* w_hh = (const float*)d_in[3];
  const float* b_ih = (const float*)d_in[4];
  const float* b_hh = (const float*)d_in[5];
  const float* w_fc = (const float*)d_in[6];
  const float* b_fc = (const float*)d_in[7];
  const float* w1   = (const float*)d_in[8];
  const float* b1   = (const float*)d_in[9];
  const float* w2   = (const float*)d_in[10];
  const float* b2   = (const float*)d_in[11];
  float* out = (float*)d_out;

  char* p = (char*)d_ws;
  auto carve = [&](size_t bytes) {
    char* r = p;
    p += (bytes + 255) & ~(size_t)255;
    return r;
  };
  char*  hxF   = carve((size_t)Bsz * 512 * 2);     // FL ca=16
  char*  hxrF  = carve((size_t)Bsz * 512 * 2);     // FL ca=16
  char*  hcatF = carve((size_t)Bsz * 1024 * 2);    // FL ca=32: h1 kg 0..15, h2 kg 16..31
  float* dxy   = (float*)carve((size_t)32 * Bsz * 4 * 4);
  float* xy    = (float*)carve((size_t)Bsz * 4 * 4);
  char*  whhF  = carve((size_t)1536 * 512 * 2);    // FL nkg=16
  char*  wfcF  = carve((size_t)512 * 1024 * 2);    // FL nkg=32
  char*  w1F   = carve((size_t)2048 * 512 * 2);    // FL nkg=16

  pack_fl<<<(1536 * 512 / 8 + 255) / 256, 256, 0, stream>>>(w_hh, whhF, 512, 4, 1536 * 512 / 8);
  pack_fl<<<(512 * 1024 / 8 + 255) / 256, 256, 0, stream>>>(w_fc, wfcF, 1024, 5, 512 * 1024 / 8);
  pack_fl<<<(2048 * 512 / 8 + 255) / 256, 256, 0, stream>>>(w1, w1F, 512, 4, 2048 * 512 / 8);
  pack_fl<<<(Bsz * 512 / 8 + 255) / 256, 256, 0, stream>>>(ptf, hxF, 512, 4, Bsz * 512 / 8);
  hipMemsetAsync(xy, 0, (size_t)Bsz * 4 * 4, stream);

  for (int i = 0; i < HORsz; ++i) {
    // h1 = GRUCell(xy, hx) -> hcat kg 0..15
    gru_fused2<<<1024, 256, 0, stream>>>(
        hxF, 16, whhF, xy, 4, w_ih, b_ih, b_hh, hcatF, 32, 0);
    // h2 = GRUCell(pv[:,i], h1) -> hcat kg 16..31
    gru_fused2<<<1024, 256, 0, stream>>>(
        hcatF, 32, whhF, pv + i * 4, HORsz * 4, w_ih, b_ih, b_hh, hcatF, 32, 16);
    // hx = hcat @ w_fc^T + b_fc ; hxr = relu(hx) (both FL, coalesced stores)
    gemm_fl2<2><<<512, 256, 0, stream>>>(
        hcatF, 32, wfcF, 32, 4, b_fc, hxF, hxrF, 16, nullptr, nullptr);
    // dxy partials = relu(relu-gemm) @ w2^T  (mlp1+mlp2 fused)
    gemm_fl2<3><<<2048, 256, 0, stream>>>(
        hxrF, 16, w1F, 16, 16, b1, nullptr, nullptr, 0, w2, dxy);
    // xy += sum + b2; out
    finalize<<<Bsz / 256, 256, 0, stream>>>(dxy, b2, xy, out, i);
  }
}

// Round 8
// 1029.394 us; speedup vs baseline: 1.8849x; 1.0413x over previous
//
#include <hip/hip_runtime.h>
#include <hip/hip_bf16.h>
#include <cstdint>
#include <cstddef>

#define Bsz 16384
#define HORsz 5

using bf16_t = __hip_bfloat16;
typedef __bf16 bf16x8 __attribute__((ext_vector_type(8)));
typedef float f32x4 __attribute__((ext_vector_type(4)));

__device__ __forceinline__ void gld_lds16(const void* g, void* l) {
  __builtin_amdgcn_global_load_lds((__attribute__((address_space(1))) void*)g,
                                   (__attribute__((address_space(3))) void*)l,
                                   16, 0, 0);
}

__device__ __forceinline__ float sigm(float x) { return 1.f / (1.f + __expf(-x)); }
__device__ __forceinline__ float tanh_fast(float x) {
  x = fminf(fmaxf(x, -20.f), 20.f);
  float e = __expf(2.f * x);
  return (e - 1.f) / (e + 1.f);
}

// XCD-aware swizzle: blocks b, b+8, b+16 ... (same XCD under b%8 round-robin)
// sweep all n-tiles of one m-tile consecutively. Requires NB_M % 8 == 0.
__device__ __forceinline__ void swz(int b, int nbn, int& n, int& m) {
  const int x = b & 7;
  const int k = b >> 3;
  n = k % nbn;
  m = x + 8 * (k / nbn);
}

// Fragment layout (FL) bf16 [R,C]: 1KB chunk = 16 rows x 32 cols; lane l <-> bytes [16l,16l+16).
__device__ __forceinline__ size_t fl_off(int row, int col, int ca, int cofs) {
  return (size_t)((row >> 4) * ca + cofs + (col >> 5)) * 1024
       + (size_t)((((col >> 3) & 3) * 16 + (row & 15)) * 16 + (col & 7) * 2);
}

// fp32 row-major [R,C] -> bf16 FL.
__global__ void __launch_bounds__(256) pack_fl(const float* __restrict__ src,
                                               char* __restrict__ dst,
                                               int C, int cs, int npieces) {
  const int p = blockIdx.x * 256 + threadIdx.x;
  if (p >= npieces) return;
  const int chunk = p >> 6, wi = p & 63;
  const int colgrp = wi >> 4, r15 = wi & 15;
  const int rowgrp = chunk >> cs, kg = chunk & ((1 << cs) - 1);
  const int row = rowgrp * 16 + r15;
  const int col = kg * 32 + colgrp * 8;
  const float* s = src + (size_t)row * C + col;
  bf16x8 v;
  #pragma unroll
  for (int j = 0; j < 8; ++j) v[j] = (__bf16)s[j];
  *(bf16x8*)(dst + (size_t)p * 16) = v;
}

// Fused GRU cell. Block: 64 rows x 64 chans x 3 gates. K-step 64 (2 chunks),
// dbuf 2 x 32KB = 64KB, 8 iterations. Wave: 64 rows x 16 chans x 3 gates.
__global__ void __launch_bounds__(256, 2) gru_fused3(
    const char* __restrict__ Afl, int ca,   // A = hprev FL, K chunks 0..15
    const char* __restrict__ Wfl,           // whh FL [1536,512], nkg=16
    const float* __restrict__ x, int ldx,   // fp32, 4 cols used
    const float* __restrict__ w_ih, const float* __restrict__ b_ih,
    const float* __restrict__ b_hh,
    char* __restrict__ Ofl, int co, int kofs)
{
  __shared__ char smem[65536];
  const int t = threadIdx.x, w = t >> 6, lane = t & 63;
  int bn, bm;
  swz(blockIdx.x, 8, bn, bm);
  const int m0 = bm * 64;
  const int n0 = bn * 64;

  // 16 chunk-slots per K-step: 0..3 = A rowgrps, 4..15 = W (gate g, colgrp cr)
  const char* gsrc[4];
  int loff[4];
  #pragma unroll
  for (int s = 0; s < 4; ++s) {
    const int idx = w * 4 + s;
    if (idx < 4) {
      gsrc[s] = Afl + (size_t)((m0 >> 4) + idx) * ca * 1024 + lane * 16;
    } else {
      const int c = idx - 4, g = c >> 2, cr = c & 3;
      gsrc[s] = Wfl + (size_t)(g * 32 + (n0 >> 4) + cr) * 16 * 1024 + lane * 16;
    }
    loff[s] = idx * 2048;
  }

  f32x4 acc[3][4];
  const f32x4 zero = {0.f, 0.f, 0.f, 0.f};
  #pragma unroll
  for (int g = 0; g < 3; ++g)
    #pragma unroll
    for (int i = 0; i < 4; ++i) acc[g][i] = zero;

  // prologue: stage kg2=0 into buf0
  #pragma unroll
  for (int s = 0; s < 4; ++s)
    #pragma unroll
    for (int sub = 0; sub < 2; ++sub)
      gld_lds16(gsrc[s] + sub * 1024, smem + loff[s] + sub * 1024);

  for (int kg2 = 0; kg2 < 8; ++kg2) {
    __syncthreads();
    const char* cur = smem + (kg2 & 1) * 32768;
    if (kg2 + 1 < 8) {
      char* nxt = smem + ((kg2 + 1) & 1) * 32768;
      #pragma unroll
      for (int s = 0; s < 4; ++s)
        #pragma unroll
        for (int sub = 0; sub < 2; ++sub)
          gld_lds16(gsrc[s] + (size_t)((kg2 + 1) * 2 + sub) * 1024, nxt + loff[s] + sub * 1024);
    }
    #pragma unroll
    for (int sub = 0; sub < 2; ++sub) {
      bf16x8 af[4];
      #pragma unroll
      for (int i = 0; i < 4; ++i)
        af[i] = *(const bf16x8*)(cur + i * 2048 + sub * 1024 + lane * 16);
      #pragma unroll
      for (int g = 0; g < 3; ++g) {
        const bf16x8 bv = *(const bf16x8*)(cur + (4 + g * 4 + w) * 2048 + sub * 1024 + lane * 16);
        #pragma unroll
        for (int i = 0; i < 4; ++i)
          acc[g][i] = __builtin_amdgcn_mfma_f32_16x16x32_bf16(af[i], bv, acc[g][i], 0, 0, 0);
      }
    }
  }

  const int lr = lane & 15, q4 = (lane >> 4) * 4;
  // buf0 free: last buf0 reads were compute(kg2=6), all waves past barrier(7).
  char* rep = smem + w * 2048;  // 4 half-chunks x 512B, wave-private
  const int c = n0 + w * 16 + lr;
  const float4 wr  = *(const float4*)(w_ih + (size_t)c * 4);
  const float4 wz  = *(const float4*)(w_ih + (size_t)(c + 512) * 4);
  const float4 wnn = *(const float4*)(w_ih + (size_t)(c + 1024) * 4);
  const float bir = b_ih[c], biz = b_ih[c + 512], bin = b_ih[c + 1024];
  const float bhr = b_hh[c], bhz = b_hh[c + 512], bhn = b_hh[c + 1024];
  const int wbase = ((lr >> 3) * 16 + q4) * 16 + (lr & 7) * 2;
  #pragma unroll
  for (int i = 0; i < 4; ++i) {
    #pragma unroll
    for (int r4 = 0; r4 < 4; ++r4) {
      const int row = m0 + i * 16 + q4 + r4;
      const float4 xv = *(const float4*)(x + (size_t)row * ldx);
      const float gir = bir + xv.x * wr.x  + xv.y * wr.y  + xv.z * wr.z  + xv.w * wr.w;
      const float giz = biz + xv.x * wz.x  + xv.y * wz.y  + xv.z * wz.z  + xv.w * wz.w;
      const float gin = bin + xv.x * wnn.x + xv.y * wnn.y + xv.z * wnn.z + xv.w * wnn.w;
      const float rr = sigm(gir + acc[0][i][r4] + bhr);
      const float zz = sigm(giz + acc[1][i][r4] + bhz);
      const float nn = tanh_fast(gin + rr * (acc[2][i][r4] + bhn));
      const float hp = (float)*(const __bf16*)(Afl + fl_off(row, c, ca, 0));
      *(__bf16*)(rep + i * 512 + wbase + r4 * 16) = (__bf16)((1.f - zz) * nn + zz * hp);
    }
  }
  // wave-private rep: same-wave LDS RAW ordered by lgkmcnt
  const int rg0 = m0 >> 4;
  const int cg = kofs + (n0 >> 5) + (w >> 1);
  const int half = (w & 1) * 512;
  #pragma unroll
  for (int i = 0; i < 4; ++i) {
    const uint2 v = *(const uint2*)(rep + i * 512 + lane * 8);
    *(uint2*)(Ofl + ((size_t)(rg0 + i) * co + cg) * 1024 + half + lane * 8) = v;
  }
}

// Generic FL GEMM, block 128x128, XCD-swizzled, K-step 64, dbuf 2x32KB.
// MODE 2 (fc):   O1 = bf16(v) FL ; O2 = bf16(relu(v)) FL — coalesced via LDS repack
// MODE 3 (mlp1): dxy[slice][row][0..3] partials of relu(v)*w2^T, slice = bn*2+(w&1)
template <int MODE>
__global__ void __launch_bounds__(256, 2) gemm_fl3(
    const char* __restrict__ Afl, int ca,
    const char* __restrict__ Bfl, int nkg, int nbn,
    const float* __restrict__ bias,
    char* __restrict__ O1, char* __restrict__ O2, int co,
    const float* __restrict__ w2, float* __restrict__ dxy)
{
  __shared__ char smem[65536];
  const int t = threadIdx.x, w = t >> 6, lane = t & 63;
  int bn, bm;
  swz(blockIdx.x, nbn, bn, bm);
  const int m0 = bm * 128, n0 = bn * 128;
  const int wm = (w >> 1) * 64, wn = (w & 1) * 64;
  const int T = nkg >> 1;

  const char* gsrc[4];
  int loff[4];
  #pragma unroll
  for (int s = 0; s < 4; ++s) {
    const int idx = w * 4 + s;
    if (idx < 8) gsrc[s] = Afl + (size_t)((m0 >> 4) + idx) * ca * 1024 + lane * 16;
    else         gsrc[s] = Bfl + (size_t)((n0 >> 4) + idx - 8) * nkg * 1024 + lane * 16;
    loff[s] = idx * 2048;
  }

  f32x4 acc[4][4];
  const f32x4 zero = {0.f, 0.f, 0.f, 0.f};
  #pragma unroll
  for (int i = 0; i < 4; ++i)
    #pragma unroll
    for (int j = 0; j < 4; ++j) acc[i][j] = zero;

  #pragma unroll
  for (int s = 0; s < 4; ++s)
    #pragma unroll
    for (int sub = 0; sub < 2; ++sub)
      gld_lds16(gsrc[s] + sub * 1024, smem + loff[s] + sub * 1024);

  for (int kg2 = 0; kg2 < T; ++kg2) {
    __syncthreads();
    const char* cur = smem + (kg2 & 1) * 32768;
    if (kg2 + 1 < T) {
      char* nxt = smem + ((kg2 + 1) & 1) * 32768;
      #pragma unroll
      for (int s = 0; s < 4; ++s)
        #pragma unroll
        for (int sub = 0; sub < 2; ++sub)
          gld_lds16(gsrc[s] + (size_t)((kg2 + 1) * 2 + sub) * 1024, nxt + loff[s] + sub * 1024);
    }
    #pragma unroll
    for (int sub = 0; sub < 2; ++sub) {
      bf16x8 af[4], bv[4];
      #pragma unroll
      for (int i = 0; i < 4; ++i)
        af[i] = *(const bf16x8*)(cur + ((wm >> 4) + i) * 2048 + sub * 1024 + lane * 16);
      #pragma unroll
      for (int j = 0; j < 4; ++j)
        bv[j] = *(const bf16x8*)(cur + (8 + (wn >> 4) + j) * 2048 + sub * 1024 + lane * 16);
      #pragma unroll
      for (int i = 0; i < 4; ++i)
        #pragma unroll
        for (int j = 0; j < 4; ++j)
          acc[i][j] = __builtin_amdgcn_mfma_f32_16x16x32_bf16(af[i], bv[j], acc[i][j], 0, 0, 0);
    }
  }

  const int lr = lane & 15, q4 = (lane >> 4) * 4;
  if (MODE == 2) {
    // buf0 free (all waves past final barrier); rep is wave-private
    char* rep = smem + w * 2048;
    const int rgb = (m0 >> 4) + (wm >> 4);
    const int cgb = (n0 >> 5) + (wn >> 5);
    for (int i = 0; i < 4; ++i) {
      #pragma unroll
      for (int j = 0; j < 4; ++j) {
        const int col = n0 + wn + j * 16 + lr;
        const float bvv = bias[col];
        const int wbase = (((j & 1) * 2 + (lr >> 3)) * 16 + q4) * 16 + (lr & 7) * 2;
        #pragma unroll
        for (int r = 0; r < 4; ++r) {
          const float v = acc[i][j][r] + bvv;
          *(__bf16*)(rep + (j >> 1) * 1024 + wbase + r * 16) = (__bf16)v;
        }
      }
      #pragma unroll
      for (int jc = 0; jc < 2; ++jc) {
        const bf16x8 v = *(const bf16x8*)(rep + jc * 1024 + lane * 16);
        const size_t cb = ((size_t)(rgb + i) * co + cgb + jc) * 1024 + lane * 16;
        *(bf16x8*)(O1 + cb) = v;
        bf16x8 vr;
        #pragma unroll
        for (int e = 0; e < 8; ++e) vr[e] = (__bf16)fmaxf((float)v[e], 0.f);
        *(bf16x8*)(O2 + cb) = vr;
      }
    }
  } else {
    const int slice = bn * 2 + (w & 1);
    #pragma unroll
    for (int i = 0; i < 4; ++i) {
      float v[4][4];   // [r][o]
      #pragma unroll
      for (int r = 0; r < 4; ++r)
        #pragma unroll
        for (int o = 0; o < 4; ++o) v[r][o] = 0.f;
      #pragma unroll
      for (int j = 0; j < 4; ++j) {
        const int col = n0 + wn + j * 16 + lr;
        const float bvv = bias[col];
        const float w20 = w2[col], w21 = w2[2048 + col], w22 = w2[4096 + col], w23 = w2[6144 + col];
        #pragma unroll
        for (int r = 0; r < 4; ++r) {
          const float pv = fmaxf(acc[i][j][r] + bvv, 0.f);
          v[r][0] += pv * w20; v[r][1] += pv * w21; v[r][2] += pv * w22; v[r][3] += pv * w23;
        }
      }
      #pragma unroll
      for (int m = 1; m <= 8; m <<= 1)
        #pragma unroll
        for (int r = 0; r < 4; ++r)
          #pragma unroll
          for (int o = 0; o < 4; ++o) v[r][o] += __shfl_xor(v[r][o], m);
      if (lr == 0) {
        #pragma unroll
        for (int r = 0; r < 4; ++r) {
          const int row = m0 + wm + i * 16 + q4 + r;
          float4 vv = make_float4(v[r][0], v[r][1], v[r][2], v[r][3]);
          *(float4*)(dxy + ((size_t)slice * Bsz + row) * 4) = vv;
        }
      }
    }
  }
}

// xy += sum(dxy slices) + b2; out[:,istep,:] = xy
__global__ void __launch_bounds__(256) finalize(
    const float* __restrict__ dxy, const float* __restrict__ b2,
    float* __restrict__ xy, float* __restrict__ out, int istep)
{
  const int b = blockIdx.x * 256 + threadIdx.x;
  float4 s = *(const float4*)b2;
  #pragma unroll 8
  for (int sl = 0; sl < 32; ++sl) {
    const float4 d = *(const float4*)(dxy + ((size_t)sl * Bsz + b) * 4);
    s.x += d.x; s.y += d.y; s.z += d.z; s.w += d.w;
  }
  float4 xv = *(const float4*)(xy + (size_t)b * 4);
  xv.x += s.x; xv.y += s.y; xv.z += s.z; xv.w += s.w;
  *(float4*)(xy + (size_t)b * 4) = xv;
  *(float4*)(out + (size_t)b * 20 + istep * 4) = xv;
}

extern "C" void kernel_launch(void* const* d_in, const int* in_sizes, int n_in,
                              void* d_out, int out_size, void* d_ws, size_t ws_size,
                              hipStream_t stream)
{
  const float* pv   = (const float*)d_in[0];
  const float* ptf  = (const float*)d_in[1];
  const float* w_ih = (const float*)d_in[2];
  const float* w_hh = (const float*)d_in[3];
  const float* b_ih = (const float*)d_in[4];
  const float* b_hh = (const float*)d_in[5];
  const float* w_fc = (const float*)d_in[6];
  const float* b_fc = (const float*)d_in[7];
  const float* w1   = (const float*)d_in[8];
  const float* b1   = (const float*)d_in[9];
  const float* w2   = (const float*)d_in[10];
  const float* b2   = (const float*)d_in[11];
  float* out = (float*)d_out;

  char* p = (char*)d_ws;
  auto carve = [&](size_t bytes) {
    char* r = p;
    p += (bytes + 255) & ~(size_t)255;
    return r;
  };
  char*  hxF   = carve((size_t)Bsz * 512 * 2);     // FL ca=16
  char*  hxrF  = carve((size_t)Bsz * 512 * 2);     // FL ca=16
  char*  hcatF = carve((size_t)Bsz * 1024 * 2);    // FL ca=32: h1 kg 0..15, h2 kg 16..31
  float* dxy   = (float*)carve((size_t)32 * Bsz * 4 * 4);
  float* xy    = (float*)carve((size_t)Bsz * 4 * 4);
  char*  whhF  = carve((size_t)1536 * 512 * 2);    // FL nkg=16
  char*  wfcF  = carve((size_t)512 * 1024 * 2);    // FL nkg=32
  char*  w1F   = carve((size_t)2048 * 512 * 2);    // FL nkg=16

  pack_fl<<<(1536 * 512 / 8 + 255) / 256, 256, 0, stream>>>(w_hh, whhF, 512, 4, 1536 * 512 / 8);
  pack_fl<<<(512 * 1024 / 8 + 255) / 256, 256, 0, stream>>>(w_fc, wfcF, 1024, 5, 512 * 1024 / 8);
  pack_fl<<<(2048 * 512 / 8 + 255) / 256, 256, 0, stream>>>(w1, w1F, 512, 4, 2048 * 512 / 8);
  pack_fl<<<(Bsz * 512 / 8 + 255) / 256, 256, 0, stream>>>(ptf, hxF, 512, 4, Bsz * 512 / 8);
  hipMemsetAsync(xy, 0, (size_t)Bsz * 4 * 4, stream);

  for (int i = 0; i < HORsz; ++i) {
    // h1 = GRUCell(xy, hx) -> hcat kg 0..15
    gru_fused3<<<2048, 256, 0, stream>>>(
        hxF, 16, whhF, xy, 4, w_ih, b_ih, b_hh, hcatF, 32, 0);
    // h2 = GRUCell(pv[:,i], h1) -> hcat kg 16..31
    gru_fused3<<<2048, 256, 0, stream>>>(
        hcatF, 32, whhF, pv + i * 4, HORsz * 4, w_ih, b_ih, b_hh, hcatF, 32, 16);
    // hx = hcat @ w_fc^T + b_fc ; hxr = relu(hx) (both FL, coalesced stores)
    gemm_fl3<2><<<512, 256, 0, stream>>>(
        hcatF, 32, wfcF, 32, 4, b_fc, hxF, hxrF, 16, nullptr, nullptr);
    // dxy partials = relu(relu-gemm) @ w2^T  (mlp1+mlp2 fused)
    gemm_fl3<3><<<2048, 256, 0, stream>>>(
        hxrF, 16, w1F, 16, 16, b1, nullptr, nullptr, 0, w2, dxy);
    // xy += sum + b2; out
    finalize<<<Bsz / 256, 256, 0, stream>>>(dxy, b2, xy, out, i);
  }
}

// Round 9
// 954.503 us; speedup vs baseline: 2.0328x; 1.0785x over previous
//
#include <hip/hip_runtime.h>
#include <hip/hip_bf16.h>
#include <cstdint>
#include <cstddef>

#define Bsz 16384
#define HORsz 5

using bf16_t = __hip_bfloat16;
typedef __bf16 bf16x8 __attribute__((ext_vector_type(8)));
typedef float f32x4 __attribute__((ext_vector_type(4)));

__device__ __forceinline__ void gld_lds16(const void* g, void* l) {
  __builtin_amdgcn_global_load_lds((__attribute__((address_space(1))) void*)g,
                                   (__attribute__((address_space(3))) void*)l,
                                   16, 0, 0);
}

__device__ __forceinline__ float sigm(float x) { return 1.f / (1.f + __expf(-x)); }
__device__ __forceinline__ float tanh_fast(float x) {
  x = fminf(fmaxf(x, -20.f), 20.f);
  float e = __expf(2.f * x);
  return (e - 1.f) / (e + 1.f);
}

// XCD-aware swizzle: blocks b, b+8, b+16 ... (same XCD under b%8 round-robin)
// sweep all n-tiles of one m-tile consecutively. Requires NB_M % 8 == 0.
__device__ __forceinline__ void swz(int b, int nbn, int& n, int& m) {
  const int x = b & 7;
  const int k = b >> 3;
  n = k % nbn;
  m = x + 8 * (k / nbn);
}

// Fragment layout (FL) bf16 [R,C]: 1KB chunk = 16 rows x 32 cols; lane l <-> bytes [16l,16l+16).
__device__ __forceinline__ size_t fl_off(int row, int col, int ca, int cofs) {
  return (size_t)((row >> 4) * ca + cofs + (col >> 5)) * 1024
       + (size_t)((((col >> 3) & 3) * 16 + (row & 15)) * 16 + (col & 7) * 2);
}

// fp32 row-major [R,C] -> bf16 FL.
__global__ void __launch_bounds__(256) pack_fl(const float* __restrict__ src,
                                               char* __restrict__ dst,
                                               int C, int cs, int npieces) {
  const int p = blockIdx.x * 256 + threadIdx.x;
  if (p >= npieces) return;
  const int chunk = p >> 6, wi = p & 63;
  const int colgrp = wi >> 4, r15 = wi & 15;
  const int rowgrp = chunk >> cs, kg = chunk & ((1 << cs) - 1);
  const int row = rowgrp * 16 + r15;
  const int col = kg * 32 + colgrp * 8;
  const float* s = src + (size_t)row * C + col;
  bf16x8 v;
  #pragma unroll
  for (int j = 0; j < 8; ++j) v[j] = (__bf16)s[j];
  *(bf16x8*)(dst + (size_t)p * 16) = v;
}

// Fused GRU cell. Block: 64 rows x 64 chans x 3 gates. K-step 32 (1 chunk/slot),
// dbuf 2 x 16KB = 32KB, 16 iterations. Wave: 64 rows x 16 chans x 3 gates.
// acc = 12 f32x4 = 48 VGPR; (256,3) caps ~170 (no spill; round 6 proved (256,4)
// cap 128 spills acc-heavy GRU to scratch).
__global__ void __launch_bounds__(256, 3) gru_fused4(
    const char* __restrict__ Afl, int ca,   // A = hprev FL, K chunks 0..15
    const char* __restrict__ Wfl,           // whh FL [1536,512], nkg=16
    const float* __restrict__ x, int ldx,   // fp32, 4 cols used
    const float* __restrict__ w_ih, const float* __restrict__ b_ih,
    const float* __restrict__ b_hh,
    char* __restrict__ Ofl, int co, int kofs)
{
  __shared__ char smem[32768];
  const int t = threadIdx.x, w = t >> 6, lane = t & 63;
  int bn, bm;
  swz(blockIdx.x, 8, bn, bm);
  const int m0 = bm * 64;
  const int n0 = bn * 64;

  // 16 chunk-slots per K-step: 0..3 = A rowgrps, 4..15 = W (gate g, colgrp cr)
  const char* gsrc[4];
  int loff[4];
  #pragma unroll
  for (int s = 0; s < 4; ++s) {
    const int idx = w * 4 + s;
    if (idx < 4) {
      gsrc[s] = Afl + (size_t)((m0 >> 4) + idx) * ca * 1024 + lane * 16;
    } else {
      const int c = idx - 4, g = c >> 2, cr = c & 3;
      gsrc[s] = Wfl + (size_t)(g * 32 + (n0 >> 4) + cr) * 16 * 1024 + lane * 16;
    }
    loff[s] = idx * 1024;
  }

  f32x4 acc[3][4];
  const f32x4 zero = {0.f, 0.f, 0.f, 0.f};
  #pragma unroll
  for (int g = 0; g < 3; ++g)
    #pragma unroll
    for (int i = 0; i < 4; ++i) acc[g][i] = zero;

  // prologue: stage kg=0 into buf0
  #pragma unroll
  for (int s = 0; s < 4; ++s)
    gld_lds16(gsrc[s], smem + loff[s]);

  for (int kg = 0; kg < 16; ++kg) {
    __syncthreads();   // stage(kg) has had one full iteration in flight
    const char* cur = smem + (kg & 1) * 16384;
    if (kg + 1 < 16) {
      char* nxt = smem + ((kg + 1) & 1) * 16384;
      #pragma unroll
      for (int s = 0; s < 4; ++s)
        gld_lds16(gsrc[s] + (size_t)(kg + 1) * 1024, nxt + loff[s]);
    }
    bf16x8 af[4];
    #pragma unroll
    for (int i = 0; i < 4; ++i)
      af[i] = *(const bf16x8*)(cur + i * 1024 + lane * 16);
    #pragma unroll
    for (int g = 0; g < 3; ++g) {
      const bf16x8 bv = *(const bf16x8*)(cur + (4 + g * 4 + w) * 1024 + lane * 16);
      #pragma unroll
      for (int i = 0; i < 4; ++i)
        acc[g][i] = __builtin_amdgcn_mfma_f32_16x16x32_bf16(af[i], bv, acc[g][i], 0, 0, 0);
    }
  }

  const int lr = lane & 15, q4 = (lane >> 4) * 4;
  // buf0 free: last buf0 read was compute(kg=14), before barrier(15); all waves
  // are past barrier(15). rep is wave-private (4 waves x 2KB = 8KB < 16KB).
  char* rep = smem + w * 2048;  // 4 half-chunks x 512B
  const int c = n0 + w * 16 + lr;
  const float4 wr  = *(const float4*)(w_ih + (size_t)c * 4);
  const float4 wz  = *(const float4*)(w_ih + (size_t)(c + 512) * 4);
  const float4 wnn = *(const float4*)(w_ih + (size_t)(c + 1024) * 4);
  const float bir = b_ih[c], biz = b_ih[c + 512], bin = b_ih[c + 1024];
  const float bhr = b_hh[c], bhz = b_hh[c + 512], bhn = b_hh[c + 1024];
  const int wbase = ((lr >> 3) * 16 + q4) * 16 + (lr & 7) * 2;
  #pragma unroll
  for (int i = 0; i < 4; ++i) {
    #pragma unroll
    for (int r4 = 0; r4 < 4; ++r4) {
      const int row = m0 + i * 16 + q4 + r4;
      const float4 xv = *(const float4*)(x + (size_t)row * ldx);
      const float gir = bir + xv.x * wr.x  + xv.y * wr.y  + xv.z * wr.z  + xv.w * wr.w;
      const float giz = biz + xv.x * wz.x  + xv.y * wz.y  + xv.z * wz.z  + xv.w * wz.w;
      const float gin = bin + xv.x * wnn.x + xv.y * wnn.y + xv.z * wnn.z + xv.w * wnn.w;
      const float rr = sigm(gir + acc[0][i][r4] + bhr);
      const float zz = sigm(giz + acc[1][i][r4] + bhz);
      const float nn = tanh_fast(gin + rr * (acc[2][i][r4] + bhn));
      const float hp = (float)*(const __bf16*)(Afl + fl_off(row, c, ca, 0));
      *(__bf16*)(rep + i * 512 + wbase + r4 * 16) = (__bf16)((1.f - zz) * nn + zz * hp);
    }
  }
  // wave-private rep: same-wave LDS RAW ordered by lgkmcnt
  const int rg0 = m0 >> 4;
  const int cg = kofs + (n0 >> 5) + (w >> 1);
  const int half = (w & 1) * 512;
  #pragma unroll
  for (int i = 0; i < 4; ++i) {
    const uint2 v = *(const uint2*)(rep + i * 512 + lane * 8);
    *(uint2*)(Ofl + ((size_t)(rg0 + i) * co + cg) * 1024 + half + lane * 8) = v;
  }
}

// Generic FL GEMM, block 128x128, XCD-swizzled, K-step 32, dbuf 2x16KB.
// (256,4): acc 64 VGPR + ~30 others fits the 128-reg cap (round 6: no spill),
// and 4 waves/EU doubles resident blocks vs (256,2) -> barrier drains overlap.
// MODE 2 (fc):   O1 = bf16(v) FL ; O2 = bf16(relu(v)) FL — coalesced via LDS repack
// MODE 3 (mlp1): dxy[slice][row][0..3] partials of relu(v)*w2^T, slice = bn*2+(w&1)
template <int MODE>
__global__ void __launch_bounds__(256, 4) gemm_fl4(
    const char* __restrict__ Afl, int ca,
    const char* __restrict__ Bfl, int nkg, int nbn,
    const float* __restrict__ bias,
    char* __restrict__ O1, char* __restrict__ O2, int co,
    const float* __restrict__ w2, float* __restrict__ dxy)
{
  __shared__ char smem[32768];
  const int t = threadIdx.x, w = t >> 6, lane = t & 63;
  int bn, bm;
  swz(blockIdx.x, nbn, bn, bm);
  const int m0 = bm * 128, n0 = bn * 128;
  const int wm = (w >> 1) * 64, wn = (w & 1) * 64;

  const char* gsrc[4];
  int loff[4];
  #pragma unroll
  for (int s = 0; s < 4; ++s) {
    const int idx = w * 4 + s;
    if (idx < 8) gsrc[s] = Afl + (size_t)((m0 >> 4) + idx) * ca * 1024 + lane * 16;
    else         gsrc[s] = Bfl + (size_t)((n0 >> 4) + idx - 8) * nkg * 1024 + lane * 16;
    loff[s] = idx * 1024;
  }

  f32x4 acc[4][4];
  const f32x4 zero = {0.f, 0.f, 0.f, 0.f};
  #pragma unroll
  for (int i = 0; i < 4; ++i)
    #pragma unroll
    for (int j = 0; j < 4; ++j) acc[i][j] = zero;

  #pragma unroll
  for (int s = 0; s < 4; ++s)
    gld_lds16(gsrc[s], smem + loff[s]);

  for (int kg = 0; kg < nkg; ++kg) {
    __syncthreads();
    const char* cur = smem + (kg & 1) * 16384;
    if (kg + 1 < nkg) {
      char* nxt = smem + ((kg + 1) & 1) * 16384;
      #pragma unroll
      for (int s = 0; s < 4; ++s)
        gld_lds16(gsrc[s] + (size_t)(kg + 1) * 1024, nxt + loff[s]);
    }
    bf16x8 af[4], bv[4];
    #pragma unroll
    for (int i = 0; i < 4; ++i)
      af[i] = *(const bf16x8*)(cur + ((wm >> 4) + i) * 1024 + lane * 16);
    #pragma unroll
    for (int j = 0; j < 4; ++j)
      bv[j] = *(const bf16x8*)(cur + (8 + (wn >> 4) + j) * 1024 + lane * 16);
    #pragma unroll
    for (int i = 0; i < 4; ++i)
      #pragma unroll
      for (int j = 0; j < 4; ++j)
        acc[i][j] = __builtin_amdgcn_mfma_f32_16x16x32_bf16(af[i], bv[j], acc[i][j], 0, 0, 0);
  }

  const int lr = lane & 15, q4 = (lane >> 4) * 4;
  if (MODE == 2) {
    // buf0 free (all waves past final barrier); rep is wave-private
    char* rep = smem + w * 2048;
    const int rgb = (m0 >> 4) + (wm >> 4);
    const int cgb = (n0 >> 5) + (wn >> 5);
    for (int i = 0; i < 4; ++i) {
      #pragma unroll
      for (int j = 0; j < 4; ++j) {
        const int col = n0 + wn + j * 16 + lr;
        const float bvv = bias[col];
        const int wbase = (((j & 1) * 2 + (lr >> 3)) * 16 + q4) * 16 + (lr & 7) * 2;
        #pragma unroll
        for (int r = 0; r < 4; ++r) {
          const float v = acc[i][j][r] + bvv;
          *(__bf16*)(rep + (j >> 1) * 1024 + wbase + r * 16) = (__bf16)v;
        }
      }
      #pragma unroll
      for (int jc = 0; jc < 2; ++jc) {
        const bf16x8 v = *(const bf16x8*)(rep + jc * 1024 + lane * 16);
        const size_t cb = ((size_t)(rgb + i) * co + cgb + jc) * 1024 + lane * 16;
        *(bf16x8*)(O1 + cb) = v;
        bf16x8 vr;
        #pragma unroll
        for (int e = 0; e < 8; ++e) vr[e] = (__bf16)fmaxf((float)v[e], 0.f);
        *(bf16x8*)(O2 + cb) = vr;
      }
    }
  } else {
    const int slice = bn * 2 + (w & 1);
    #pragma unroll
    for (int i = 0; i < 4; ++i) {
      float v[4][4];   // [r][o]
      #pragma unroll
      for (int r = 0; r < 4; ++r)
        #pragma unroll
        for (int o = 0; o < 4; ++o) v[r][o] = 0.f;
      #pragma unroll
      for (int j = 0; j < 4; ++j) {
        const int col = n0 + wn + j * 16 + lr;
        const float bvv = bias[col];
        const float w20 = w2[col], w21 = w2[2048 + col], w22 = w2[4096 + col], w23 = w2[6144 + col];
        #pragma unroll
        for (int r = 0; r < 4; ++r) {
          const float pv = fmaxf(acc[i][j][r] + bvv, 0.f);
          v[r][0] += pv * w20; v[r][1] += pv * w21; v[r][2] += pv * w22; v[r][3] += pv * w23;
        }
      }
      #pragma unroll
      for (int m = 1; m <= 8; m <<= 1)
        #pragma unroll
        for (int r = 0; r < 4; ++r)
          #pragma unroll
          for (int o = 0; o < 4; ++o) v[r][o] += __shfl_xor(v[r][o], m);
      if (lr == 0) {
        #pragma unroll
        for (int r = 0; r < 4; ++r) {
          const int row = m0 + wm + i * 16 + q4 + r;
          float4 vv = make_float4(v[r][0], v[r][1], v[r][2], v[r][3]);
          *(float4*)(dxy + ((size_t)slice * Bsz + row) * 4) = vv;
        }
      }
    }
  }
}

// xy += sum(dxy slices) + b2; out[:,istep,:] = xy
__global__ void __launch_bounds__(256) finalize(
    const float* __restrict__ dxy, const float* __restrict__ b2,
    float* __restrict__ xy, float* __restrict__ out, int istep)
{
  const int b = blockIdx.x * 256 + threadIdx.x;
  float4 s = *(const float4*)b2;
  #pragma unroll 8
  for (int sl = 0; sl < 32; ++sl) {
    const float4 d = *(const float4*)(dxy + ((size_t)sl * Bsz + b) * 4);
    s.x += d.x; s.y += d.y; s.z += d.z; s.w += d.w;
  }
  float4 xv = *(const float4*)(xy + (size_t)b * 4);
  xv.x += s.x; xv.y += s.y; xv.z += s.z; xv.w += s.w;
  *(float4*)(xy + (size_t)b * 4) = xv;
  *(float4*)(out + (size_t)b * 20 + istep * 4) = xv;
}

extern "C" void kernel_launch(void* const* d_in, const int* in_sizes, int n_in,
                              void* d_out, int out_size, void* d_ws, size_t ws_size,
                              hipStream_t stream)
{
  const float* pv   = (const float*)d_in[0];
  const float* ptf  = (const float*)d_in[1];
  const float* w_ih = (const float*)d_in[2];
  const float* w_hh = (const float*)d_in[3];
  const float* b_ih = (const float*)d_in[4];
  const float* b_hh = (const float*)d_in[5];
  const float* w_fc = (const float*)d_in[6];
  const float* b_fc = (const float*)d_in[7];
  const float* w1   = (const float*)d_in[8];
  const float* b1   = (const float*)d_in[9];
  const float* w2   = (const float*)d_in[10];
  const float* b2   = (const float*)d_in[11];
  float* out = (float*)d_out;

  char* p = (char*)d_ws;
  auto carve = [&](size_t bytes) {
    char* r = p;
    p += (bytes + 255) & ~(size_t)255;
    return r;
  };
  char*  hxF   = carve((size_t)Bsz * 512 * 2);     // FL ca=16
  char*  hxrF  = carve((size_t)Bsz * 512 * 2);     // FL ca=16
  char*  hcatF = carve((size_t)Bsz * 1024 * 2);    // FL ca=32: h1 kg 0..15, h2 kg 16..31
  float* dxy   = (float*)carve((size_t)32 * Bsz * 4 * 4);
  float* xy    = (float*)carve((size_t)Bsz * 4 * 4);
  char*  whhF  = carve((size_t)1536 * 512 * 2);    // FL nkg=16
  char*  wfcF  = carve((size_t)512 * 1024 * 2);    // FL nkg=32
  char*  w1F   = carve((size_t)2048 * 512 * 2);    // FL nkg=16

  pack_fl<<<(1536 * 512 / 8 + 255) / 256, 256, 0, stream>>>(w_hh, whhF, 512, 4, 1536 * 512 / 8);
  pack_fl<<<(512 * 1024 / 8 + 255) / 256, 256, 0, stream>>>(w_fc, wfcF, 1024, 5, 512 * 1024 / 8);
  pack_fl<<<(2048 * 512 / 8 + 255) / 256, 256, 0, stream>>>(w1, w1F, 512, 4, 2048 * 512 / 8);
  pack_fl<<<(Bsz * 512 / 8 + 255) / 256, 256, 0, stream>>>(ptf, hxF, 512, 4, Bsz * 512 / 8);
  hipMemsetAsync(xy, 0, (size_t)Bsz * 4 * 4, stream);

  for (int i = 0; i < HORsz; ++i) {
    // h1 = GRUCell(xy, hx) -> hcat kg 0..15
    gru_fused4<<<2048, 256, 0, stream>>>(
        hxF, 16, whhF, xy, 4, w_ih, b_ih, b_hh, hcatF, 32, 0);
    // h2 = GRUCell(pv[:,i], h1) -> hcat kg 16..31
    gru_fused4<<<2048, 256, 0, stream>>>(
        hcatF, 32, whhF, pv + i * 4, HORsz * 4, w_ih, b_ih, b_hh, hcatF, 32, 16);
    // hx = hcat @ w_fc^T + b_fc ; hxr = relu(hx) (both FL, coalesced stores)
    gemm_fl4<2><<<512, 256, 0, stream>>>(
        hcatF, 32, wfcF, 32, 4, b_fc, hxF, hxrF, 16, nullptr, nullptr);
    // dxy partials = relu(relu-gemm) @ w2^T  (mlp1+mlp2 fused)
    gemm_fl4<3><<<2048, 256, 0, stream>>>(
        hxrF, 16, w1F, 16, 16, b1, nullptr, nullptr, 0, w2, dxy);
    // xy += sum + b2; out
    finalize<<<Bsz / 256, 256, 0, stream>>>(dxy, b2, xy, out, i);
  }
}

// Round 10
// 945.566 us; speedup vs baseline: 2.0520x; 1.0095x over previous
//
#include <hip/hip_runtime.h>
#include <hip/hip_bf16.h>
#include <cstdint>
#include <cstddef>

#define Bsz 16384
#define HORsz 5

using bf16_t = __hip_bfloat16;
typedef __bf16 bf16x8 __attribute__((ext_vector_type(8)));
typedef float f32x4 __attribute__((ext_vector_type(4)));

__device__ __forceinline__ void gld_lds16(const void* g, void* l) {
  __builtin_amdgcn_global_load_lds((__attribute__((address_space(1))) void*)g,
                                   (__attribute__((address_space(3))) void*)l,
                                   16, 0, 0);
}

__device__ __forceinline__ float sigm(float x) { return 1.f / (1.f + __expf(-x)); }
__device__ __forceinline__ float tanh_fast(float x) {
  x = fminf(fmaxf(x, -20.f), 20.f);
  float e = __expf(2.f * x);
  return (e - 1.f) / (e + 1.f);
}

// XCD-aware swizzle: blocks b, b+8, b+16 ... (same XCD under b%8 round-robin)
// sweep all n-tiles of one m-tile consecutively. Requires NB_M % 8 == 0.
__device__ __forceinline__ void swz(int b, int nbn, int& n, int& m) {
  const int x = b & 7;
  const int k = b >> 3;
  n = k % nbn;
  m = x + 8 * (k / nbn);
}

// Fragment layout (FL) bf16 [R,C]: 1KB chunk = 16 rows x 32 cols; lane l <-> bytes [16l,16l+16).
__device__ __forceinline__ size_t fl_off(int row, int col, int ca, int cofs) {
  return (size_t)((row >> 4) * ca + cofs + (col >> 5)) * 1024
       + (size_t)((((col >> 3) & 3) * 16 + (row & 15)) * 16 + (col & 7) * 2);
}

// fp32 row-major [R,C] -> bf16 FL.
__global__ void __launch_bounds__(256) pack_fl(const float* __restrict__ src,
                                               char* __restrict__ dst,
                                               int C, int cs, int npieces) {
  const int p = blockIdx.x * 256 + threadIdx.x;
  if (p >= npieces) return;
  const int chunk = p >> 6, wi = p & 63;
  const int colgrp = wi >> 4, r15 = wi & 15;
  const int rowgrp = chunk >> cs, kg = chunk & ((1 << cs) - 1);
  const int row = rowgrp * 16 + r15;
  const int col = kg * 32 + colgrp * 8;
  const float* s = src + (size_t)row * C + col;
  bf16x8 v;
  #pragma unroll
  for (int j = 0; j < 8; ++j) v[j] = (__bf16)s[j];
  *(bf16x8*)(dst + (size_t)p * 16) = v;
}

// Fused GRU cell. Block: 64 rows x 64 chans x 3 gates. K-step 32, dbuf 2x16KB,
// 16 fully-unrolled iterations. (256,3): cap ~170, no spill (acc=48).
__global__ void __launch_bounds__(256, 3) gru_fused4(
    const char* __restrict__ Afl, int ca,   // A = hprev FL, K chunks 0..15
    const char* __restrict__ Wfl,           // whh FL [1536,512], nkg=16
    const float* __restrict__ x, int ldx,   // fp32, 4 cols used
    const float* __restrict__ w_ih, const float* __restrict__ b_ih,
    const float* __restrict__ b_hh,
    char* __restrict__ Ofl, int co, int kofs)
{
  __shared__ char smem[32768];
  const int t = threadIdx.x, w = t >> 6, lane = t & 63;
  int bn, bm;
  swz(blockIdx.x, 8, bn, bm);
  const int m0 = bm * 64;
  const int n0 = bn * 64;

  // 16 chunk-slots per K-step: 0..3 = A rowgrps, 4..15 = W (gate g, colgrp cr)
  const char* gsrc[4];
  int loff[4];
  #pragma unroll
  for (int s = 0; s < 4; ++s) {
    const int idx = w * 4 + s;
    if (idx < 4) {
      gsrc[s] = Afl + (size_t)((m0 >> 4) + idx) * ca * 1024 + lane * 16;
    } else {
      const int c = idx - 4, g = c >> 2, cr = c & 3;
      gsrc[s] = Wfl + (size_t)(g * 32 + (n0 >> 4) + cr) * 16 * 1024 + lane * 16;
    }
    loff[s] = idx * 1024;
  }

  f32x4 acc[3][4];
  const f32x4 zero = {0.f, 0.f, 0.f, 0.f};
  #pragma unroll
  for (int g = 0; g < 3; ++g)
    #pragma unroll
    for (int i = 0; i < 4; ++i) acc[g][i] = zero;

  #pragma unroll
  for (int s = 0; s < 4; ++s)
    gld_lds16(gsrc[s], smem + loff[s]);

  #pragma unroll
  for (int kg = 0; kg < 16; ++kg) {
    __syncthreads();   // stage(kg) has had one full iteration in flight
    const char* cur = smem + (kg & 1) * 16384;
    if (kg + 1 < 16) {
      char* nxt = smem + ((kg + 1) & 1) * 16384;
      #pragma unroll
      for (int s = 0; s < 4; ++s)
        gld_lds16(gsrc[s] + (size_t)(kg + 1) * 1024, nxt + loff[s]);
    }
    bf16x8 af[4];
    #pragma unroll
    for (int i = 0; i < 4; ++i)
      af[i] = *(const bf16x8*)(cur + i * 1024 + lane * 16);
    #pragma unroll
    for (int g = 0; g < 3; ++g) {
      const bf16x8 bv = *(const bf16x8*)(cur + (4 + g * 4 + w) * 1024 + lane * 16);
      #pragma unroll
      for (int i = 0; i < 4; ++i)
        acc[g][i] = __builtin_amdgcn_mfma_f32_16x16x32_bf16(af[i], bv, acc[g][i], 0, 0, 0);
    }
  }

  const int lr = lane & 15, q4 = (lane >> 4) * 4;
  // buf0 free: last buf0 read was compute(kg=14); all waves past barrier(15).
  char* rep = smem + w * 2048;  // 4 half-chunks x 512B, wave-private
  const int c = n0 + w * 16 + lr;
  const float4 wr  = *(const float4*)(w_ih + (size_t)c * 4);
  const float4 wz  = *(const float4*)(w_ih + (size_t)(c + 512) * 4);
  const float4 wnn = *(const float4*)(w_ih + (size_t)(c + 1024) * 4);
  const float bir = b_ih[c], biz = b_ih[c + 512], bin = b_ih[c + 1024];
  const float bhr = b_hh[c], bhz = b_hh[c + 512], bhn = b_hh[c + 1024];
  const int wbase = ((lr >> 3) * 16 + q4) * 16 + (lr & 7) * 2;
  #pragma unroll
  for (int i = 0; i < 4; ++i) {
    #pragma unroll
    for (int r4 = 0; r4 < 4; ++r4) {
      const int row = m0 + i * 16 + q4 + r4;
      const float4 xv = *(const float4*)(x + (size_t)row * ldx);
      const float gir = bir + xv.x * wr.x  + xv.y * wr.y  + xv.z * wr.z  + xv.w * wr.w;
      const float giz = biz + xv.x * wz.x  + xv.y * wz.y  + xv.z * wz.z  + xv.w * wz.w;
      const float gin = bin + xv.x * wnn.x + xv.y * wnn.y + xv.z * wnn.z + xv.w * wnn.w;
      const float rr = sigm(gir + acc[0][i][r4] + bhr);
      const float zz = sigm(giz + acc[1][i][r4] + bhz);
      const float nn = tanh_fast(gin + rr * (acc[2][i][r4] + bhn));
      const float hp = (float)*(const __bf16*)(Afl + fl_off(row, c, ca, 0));
      *(__bf16*)(rep + i * 512 + wbase + r4 * 16) = (__bf16)((1.f - zz) * nn + zz * hp);
    }
  }
  const int rg0 = m0 >> 4;
  const int cg = kofs + (n0 >> 5) + (w >> 1);
  const int half = (w & 1) * 512;
  #pragma unroll
  for (int i = 0; i < 4; ++i) {
    const uint2 v = *(const uint2*)(rep + i * 512 + lane * 8);
    *(uint2*)(Ofl + ((size_t)(rg0 + i) * co + cg) * 1024 + half + lane * 8) = v;
  }
}

// Generic FL GEMM. Block tile 128 x (NJ*32); wave tile 64 x (NJ*16).
// NKG = K/32 compile-time (full unroll). A chunk-stride == B chunk-stride == NKG.
// MODE 2 (fc):   O1 = bf16(v) FL ; O2 = bf16(relu(v)) FL — coalesced via LDS repack
// MODE 3 (mlp1): dxy[slice][row][0..3] partials of relu(v)*w2^T, slice = bn*2+(w&1)
template <int NKG, int NJ, int MODE>
__global__ void __launch_bounds__(256, 4) gemm_fl5(
    const char* __restrict__ Afl,
    const char* __restrict__ Bfl, int nbn,
    const float* __restrict__ bias,
    char* __restrict__ O1, char* __restrict__ O2, int co,
    const float* __restrict__ w2, float* __restrict__ dxy)
{
  constexpr int NCH = 8 + 2 * NJ;          // chunks staged per K-step
  constexpr int NS = NCH / 4;              // chunks per wave
  constexpr int BUFB = NCH * 1024;
  __shared__ char smem[2 * BUFB];
  const int t = threadIdx.x, w = t >> 6, lane = t & 63;
  int bn, bm;
  swz(blockIdx.x, nbn, bn, bm);
  const int m0 = bm * 128, n0 = bn * (NJ * 32);
  const int wm = (w >> 1) * 64, wn = (w & 1) * (NJ * 16);

  const char* gsrc[NS];
  int loff[NS];
  #pragma unroll
  for (int s = 0; s < NS; ++s) {
    const int idx = w * NS + s;
    if (idx < 8) gsrc[s] = Afl + (size_t)((m0 >> 4) + idx) * NKG * 1024 + lane * 16;
    else         gsrc[s] = Bfl + (size_t)((n0 >> 4) + idx - 8) * NKG * 1024 + lane * 16;
    loff[s] = idx * 1024;
  }

  f32x4 acc[4][NJ];
  const f32x4 zero = {0.f, 0.f, 0.f, 0.f};
  #pragma unroll
  for (int i = 0; i < 4; ++i)
    #pragma unroll
    for (int j = 0; j < NJ; ++j) acc[i][j] = zero;

  #pragma unroll
  for (int s = 0; s < NS; ++s)
    gld_lds16(gsrc[s], smem + loff[s]);

  #pragma unroll
  for (int kg = 0; kg < NKG; ++kg) {
    __syncthreads();
    const char* cur = smem + (kg & 1) * BUFB;
    if (kg + 1 < NKG) {
      char* nxt = smem + ((kg + 1) & 1) * BUFB;
      #pragma unroll
      for (int s = 0; s < NS; ++s)
        gld_lds16(gsrc[s] + (size_t)(kg + 1) * 1024, nxt + loff[s]);
    }
    bf16x8 af[4], bv[NJ];
    #pragma unroll
    for (int i = 0; i < 4; ++i)
      af[i] = *(const bf16x8*)(cur + ((wm >> 4) + i) * 1024 + lane * 16);
    #pragma unroll
    for (int j = 0; j < NJ; ++j)
      bv[j] = *(const bf16x8*)(cur + (8 + (wn >> 4) + j) * 1024 + lane * 16);
    #pragma unroll
    for (int i = 0; i < 4; ++i)
      #pragma unroll
      for (int j = 0; j < NJ; ++j)
        acc[i][j] = __builtin_amdgcn_mfma_f32_16x16x32_bf16(af[i], bv[j], acc[i][j], 0, 0, 0);
  }

  const int lr = lane & 15, q4 = (lane >> 4) * 4;
  if (MODE == 2) {
    // buf0 free (all waves past final barrier); rep is wave-private
    char* rep = smem + w * (NJ / 2) * 1024;
    const int rgb = (m0 >> 4) + (wm >> 4);
    const int cgb = (n0 >> 5) + (wn >> 5);
    for (int i = 0; i < 4; ++i) {
      #pragma unroll
      for (int j = 0; j < NJ; ++j) {
        const int col = n0 + wn + j * 16 + lr;
        const float bvv = bias[col];
        const int wbase = (((j & 1) * 2 + (lr >> 3)) * 16 + q4) * 16 + (lr & 7) * 2;
        #pragma unroll
        for (int r = 0; r < 4; ++r) {
          const float v = acc[i][j][r] + bvv;
          *(__bf16*)(rep + (j >> 1) * 1024 + wbase + r * 16) = (__bf16)v;
        }
      }
      #pragma unroll
      for (int jc = 0; jc < NJ / 2; ++jc) {
        const bf16x8 v = *(const bf16x8*)(rep + jc * 1024 + lane * 16);
        const size_t cb = ((size_t)(rgb + i) * co + cgb + jc) * 1024 + lane * 16;
        *(bf16x8*)(O1 + cb) = v;
        bf16x8 vr;
        #pragma unroll
        for (int e = 0; e < 8; ++e) vr[e] = (__bf16)fmaxf((float)v[e], 0.f);
        *(bf16x8*)(O2 + cb) = vr;
      }
    }
  } else {
    const int slice = bn * 2 + (w & 1);
    #pragma unroll
    for (int i = 0; i < 4; ++i) {
      float v[4][4];   // [r][o]
      #pragma unroll
      for (int r = 0; r < 4; ++r)
        #pragma unroll
        for (int o = 0; o < 4; ++o) v[r][o] = 0.f;
      #pragma unroll
      for (int j = 0; j < NJ; ++j) {
        const int col = n0 + wn + j * 16 + lr;
        const float bvv = bias[col];
        const float w20 = w2[col], w21 = w2[2048 + col], w22 = w2[4096 + col], w23 = w2[6144 + col];
        #pragma unroll
        for (int r = 0; r < 4; ++r) {
          const float pv = fmaxf(acc[i][j][r] + bvv, 0.f);
          v[r][0] += pv * w20; v[r][1] += pv * w21; v[r][2] += pv * w22; v[r][3] += pv * w23;
        }
      }
      #pragma unroll
      for (int m = 1; m <= 8; m <<= 1)
        #pragma unroll
        for (int r = 0; r < 4; ++r)
          #pragma unroll
          for (int o = 0; o < 4; ++o) v[r][o] += __shfl_xor(v[r][o], m);
      if (lr == 0) {
        #pragma unroll
        for (int r = 0; r < 4; ++r) {
          const int row = m0 + wm + i * 16 + q4 + r;
          float4 vv = make_float4(v[r][0], v[r][1], v[r][2], v[r][3]);
          *(float4*)(dxy + ((size_t)slice * Bsz + row) * 4) = vv;
        }
      }
    }
  }
}

// xy += sum(dxy slices) + b2; out[:,istep,:] = xy
__global__ void __launch_bounds__(256) finalize(
    const float* __restrict__ dxy, const float* __restrict__ b2,
    float* __restrict__ xy, float* __restrict__ out, int istep)
{
  const int b = blockIdx.x * 256 + threadIdx.x;
  float4 s = *(const float4*)b2;
  #pragma unroll 8
  for (int sl = 0; sl < 32; ++sl) {
    const float4 d = *(const float4*)(dxy + ((size_t)sl * Bsz + b) * 4);
    s.x += d.x; s.y += d.y; s.z += d.z; s.w += d.w;
  }
  float4 xv = *(const float4*)(xy + (size_t)b * 4);
  xv.x += s.x; xv.y += s.y; xv.z += s.z; xv.w += s.w;
  *(float4*)(xy + (size_t)b * 4) = xv;
  *(float4*)(out + (size_t)b * 20 + istep * 4) = xv;
}

extern "C" void kernel_launch(void* const* d_in, const int* in_sizes, int n_in,
                              void* d_out, int out_size, void* d_ws, size_t ws_size,
                              hipStream_t stream)
{
  const float* pv   = (const float*)d_in[0];
  const float* ptf  = (const float*)d_in[1];
  const float* w_ih = (const float*)d_in[2];
  const float* w_hh = (const float*)d_in[3];
  const float* b_ih = (const float*)d_in[4];
  const float* b_hh = (const float*)d_in[5];
  const float* w_fc = (const float*)d_in[6];
  const float* b_fc = (const float*)d_in[7];
  const float* w1   = (const float*)d_in[8];
  const float* b1   = (const float*)d_in[9];
  const float* w2   = (const float*)d_in[10];
  const float* b2   = (const float*)d_in[11];
  float* out = (float*)d_out;

  char* p = (char*)d_ws;
  auto carve = [&](size_t bytes) {
    char* r = p;
    p += (bytes + 255) & ~(size_t)255;
    return r;
  };
  char*  hxF   = carve((size_t)Bsz * 512 * 2);     // FL ca=16
  char*  hxrF  = carve((size_t)Bsz * 512 * 2);     // FL ca=16
  char*  hcatF = carve((size_t)Bsz * 1024 * 2);    // FL ca=32: h1 kg 0..15, h2 kg 16..31
  float* dxy   = (float*)carve((size_t)32 * Bsz * 4 * 4);
  float* xy    = (float*)carve((size_t)Bsz * 4 * 4);
  char*  whhF  = carve((size_t)1536 * 512 * 2);    // FL nkg=16
  char*  wfcF  = carve((size_t)512 * 1024 * 2);    // FL nkg=32
  char*  w1F   = carve((size_t)2048 * 512 * 2);    // FL nkg=16

  pack_fl<<<(1536 * 512 / 8 + 255) / 256, 256, 0, stream>>>(w_hh, whhF, 512, 4, 1536 * 512 / 8);
  pack_fl<<<(512 * 1024 / 8 + 255) / 256, 256, 0, stream>>>(w_fc, wfcF, 1024, 5, 512 * 1024 / 8);
  pack_fl<<<(2048 * 512 / 8 + 255) / 256, 256, 0, stream>>>(w1, w1F, 512, 4, 2048 * 512 / 8);
  pack_fl<<<(Bsz * 512 / 8 + 255) / 256, 256, 0, stream>>>(ptf, hxF, 512, 4, Bsz * 512 / 8);
  hipMemsetAsync(xy, 0, (size_t)Bsz * 4 * 4, stream);

  for (int i = 0; i < HORsz; ++i) {
    // h1 = GRUCell(xy, hx) -> hcat kg 0..15
    gru_fused4<<<2048, 256, 0, stream>>>(
        hxF, 16, whhF, xy, 4, w_ih, b_ih, b_hh, hcatF, 32, 0);
    // h2 = GRUCell(pv[:,i], h1) -> hcat kg 16..31
    gru_fused4<<<2048, 256, 0, stream>>>(
        hcatF, 32, whhF, pv + i * 4, HORsz * 4, w_ih, b_ih, b_hh, hcatF, 32, 16);
    // hx = hcat @ w_fc^T + b_fc ; hxr = relu(hx)  (K=1024 -> NKG=32, 64-wide n-tiles, grid 1024)
    gemm_fl5<32, 2, 2><<<1024, 256, 0, stream>>>(
        hcatF, wfcF, 8, b_fc, hxF, hxrF, 16, nullptr, nullptr);
    // dxy partials = relu(relu-gemm) @ w2^T  (mlp1+mlp2 fused; K=512 -> NKG=16)
    gemm_fl5<16, 4, 3><<<2048, 256, 0, stream>>>(
        hxrF, w1F, 16, b1, nullptr, nullptr, 0, w2, dxy);
    // xy += sum + b2; out
    finalize<<<Bsz / 256, 256, 0, stream>>>(dxy, b2, xy, out, i);
  }
}